// Round 2
// baseline (1212.281 us; speedup 1.0000x reference)
//
#include <hip/hip_runtime.h>
#include <hip/hip_bf16.h>

#define M_DIM 4096
#define N_DIM 8192
#define K_DIM 8192

using bf16x8 = __attribute__((ext_vector_type(8))) short;
using f32x4  = __attribute__((ext_vector_type(4))) float;

static __device__ __forceinline__ unsigned short f32_to_bf16_rne(float f) {
    unsigned u = __float_as_uint(f);
    unsigned rounding = 0x7FFFu + ((u >> 16) & 1u);
    u += rounding;
    return (unsigned short)(u >> 16);
}

// ---------------- zero W (f32) ----------------
__global__ void zero_kernel(float4* __restrict__ p, int n4) {
    int i = blockIdx.x * blockDim.x + threadIdx.x;
    int stride = gridDim.x * blockDim.x;
    float4 z = make_float4(0.f, 0.f, 0.f, 0.f);
    for (; i < n4; i += stride) p[i] = z;
}

// ---------------- scatter-add COO ----------------
__global__ void scatter_kernel(const float* __restrict__ vals,
                               const int* __restrict__ rows,
                               const int* __restrict__ cols,
                               float* __restrict__ W, int n) {
    int i = blockIdx.x * blockDim.x + threadIdx.x;
    if (i < n) {
        atomicAdd(&W[(size_t)rows[i] * K_DIM + cols[i]], vals[i]);
    }
}

// ---------------- f32 -> bf16 cast ----------------
__global__ void cvt_bf16_kernel(const float4* __restrict__ src,
                                ushort4* __restrict__ dst, int n4) {
    int i = blockIdx.x * blockDim.x + threadIdx.x;
    int stride = gridDim.x * blockDim.x;
    for (; i < n4; i += stride) {
        float4 v = src[i];
        ushort4 o;
        o.x = f32_to_bf16_rne(v.x);
        o.y = f32_to_bf16_rne(v.y);
        o.z = f32_to_bf16_rne(v.z);
        o.w = f32_to_bf16_rne(v.w);
        dst[i] = o;
    }
}

// ---------------- zero d_out fallback (ws too small diagnostic) ----------------
__global__ void zero_out_kernel(float* __restrict__ p, int n) {
    int i = blockIdx.x * blockDim.x + threadIdx.x;
    int stride = gridDim.x * blockDim.x;
    for (; i < n; i += stride) p[i] = 0.f;
}

// ---------------- bf16 NT GEMM: C[M][N] = A[M][K] * B[N][K]^T ----------------
// 128x128 tile, BK=32, 4 waves (2x2), each wave 64x64 via 4x4 16x16x32 MFMAs.
// LDS k-chunk swizzle (T2, rule #21): LDS slot (row, c) holds global k-chunk
// c ^ ((row>>1)&3). global_load_lds dest stays linear; the SOURCE address is
// pre-swizzled and the ds_read applies the same involution. Bank-quad index
// becomes 4*(row&1) + (g ^ ((row>>1)&3)): 16 lanes -> 8 quads, 2/quad = free.
__global__ __launch_bounds__(256) void gemm_bt(const ushort* __restrict__ A,
                                               const ushort* __restrict__ B,
                                               float* __restrict__ C) {
    constexpr int BM = 128, BN = 128, BK = 32;
    __shared__ ushort As[BM][BK];  // 8 KB
    __shared__ ushort Bs[BN][BK];  // 8 KB

    // T1: XCD-chunked block swizzle. nwg = 2048, 2048 % 8 == 0 -> bijective.
    const int nwg = (M_DIM / BM) * (N_DIM / BN);   // 2048
    const int cpx = nwg / 8;                       // 256 tiles per XCD
    const int bid = blockIdx.x;
    const int tile = (bid % 8) * cpx + (bid / 8);

    const int nbn = N_DIM / BN;            // 64
    const int bm = tile / nbn;
    const int bn = tile % nbn;
    const int brow = bm * BM, bcol = bn * BN;

    const int t = threadIdx.x;
    const int lane = t & 63;
    const int w = t >> 6;                  // wave 0..3
    const int wm = w >> 1, wn = w & 1;     // 2x2 wave grid
    const int lrow = lane & 15;            // fragment row within 16
    const int g = lane >> 4;               // k-chunk group 0..3

    f32x4 acc[4][4] = {};

    for (int kt = 0; kt < K_DIM; kt += BK) {
        // ---- stage A and B tiles: 512 x 16B chunks each ----
        // flat chunk fl -> LDS bytes [fl*16, fl*16+16): linear dest per wave.
        // Source k-chunk is XOR-swizzled per row.
        #pragma unroll
        for (int c = 0; c < 2; ++c) {
            int fl = c * 256 + t;          // 0..511
            int row = fl >> 2;             // 4 chunks (32 bf16) per row
            int cc = fl & 3;
            int kk = (cc ^ ((row >> 1) & 3)) * 8;
            const ushort* ga = A + (size_t)(brow + row) * K_DIM + kt + kk;
            __builtin_amdgcn_global_load_lds(
                (const __attribute__((address_space(1))) void*)ga,
                (__attribute__((address_space(3))) void*)(&As[0][0] + fl * 8),
                16, 0, 0);
            const ushort* gb = B + (size_t)(bcol + row) * K_DIM + kt + kk;
            __builtin_amdgcn_global_load_lds(
                (const __attribute__((address_space(1))) void*)gb,
                (__attribute__((address_space(3))) void*)(&Bs[0][0] + fl * 8),
                16, 0, 0);
        }
        __syncthreads();

        bf16x8 af[4], bfr[4];
        #pragma unroll
        for (int m = 0; m < 4; ++m) {
            int row = wm * 64 + m * 16 + lrow;
            int cA = g ^ ((row >> 1) & 3);
            af[m] = *(const bf16x8*)&As[row][cA * 8];
        }
        #pragma unroll
        for (int n = 0; n < 4; ++n) {
            int row = wn * 64 + n * 16 + lrow;
            int cB = g ^ ((row >> 1) & 3);
            bfr[n] = *(const bf16x8*)&Bs[row][cB * 8];
        }

        #pragma unroll
        for (int m = 0; m < 4; ++m)
            #pragma unroll
            for (int n = 0; n < 4; ++n)
                acc[m][n] = __builtin_amdgcn_mfma_f32_16x16x32_bf16(
                    af[m], bfr[n], acc[m][n], 0, 0, 0);
        __syncthreads();
    }

    // ---- epilogue: C/D layout col=lane&15, row=(lane>>4)*4+r ----
    const int crow0 = brow + wm * 64;
    const int ccol0 = bcol + wn * 64;
    #pragma unroll
    for (int m = 0; m < 4; ++m) {
        #pragma unroll
        for (int n = 0; n < 4; ++n) {
            int col = ccol0 + n * 16 + (lane & 15);
            int rbase = crow0 + m * 16 + (lane >> 4) * 4;
            #pragma unroll
            for (int r = 0; r < 4; ++r)
                C[(size_t)(rbase + r) * N_DIM + col] = acc[m][n][r];
        }
    }
}

extern "C" void kernel_launch(void* const* d_in, const int* in_sizes, int n_in,
                              void* d_out, int out_size, void* d_ws, size_t ws_size,
                              hipStream_t stream) {
    const float* x    = (const float*)d_in[0];
    const float* vals = (const float*)d_in[1];
    const int* rows   = (const int*)d_in[2];
    const int* cols   = (const int*)d_in[3];
    float* out        = (float*)d_out;
    const int n_items = in_sizes[1];

    const size_t W_F32_BYTES  = (size_t)N_DIM * K_DIM * 4;  // 256 MiB
    const size_t W_BF16_BYTES = (size_t)N_DIM * K_DIM * 2;  // 128 MiB
    const size_t X_BF16_BYTES = (size_t)M_DIM * K_DIM * 2;  //  64 MiB
    const size_t NEEDED = W_F32_BYTES + W_BF16_BYTES + X_BF16_BYTES;

    if (ws_size < NEEDED) {
        // Diagnostic fallback: clean absmax=126 failure signals ws too small.
        zero_out_kernel<<<2048, 256, 0, stream>>>(out, out_size);
        return;
    }

    char* ws = (char*)d_ws;
    float* Wf  = (float*)ws;
    ushort* Wb = (ushort*)(ws + W_F32_BYTES);
    ushort* Xb = (ushort*)(ws + W_F32_BYTES + W_BF16_BYTES);

    // 1) zero W (re-zeroed every call: deterministic under replay)
    zero_kernel<<<2048, 256, 0, stream>>>((float4*)Wf, (N_DIM * K_DIM) / 4);
    // 2) scatter-add nonzeros
    scatter_kernel<<<(n_items + 255) / 256, 256, 0, stream>>>(vals, rows, cols, Wf, n_items);
    // 3) cast W and x to bf16
    cvt_bf16_kernel<<<2048, 256, 0, stream>>>((const float4*)Wf, (ushort4*)Wb,
                                              (N_DIM * K_DIM) / 4);
    cvt_bf16_kernel<<<2048, 256, 0, stream>>>((const float4*)x, (ushort4*)Xb,
                                              (M_DIM * K_DIM) / 4);
    // 4) GEMM: out = Xb (M x K) * Wb (N x K)^T
    gemm_bt<<<(M_DIM / 128) * (N_DIM / 128), 256, 0, stream>>>(Xb, Wb, out);
}

// Round 3
// 728.952 us; speedup vs baseline: 1.6630x; 1.6630x over previous
//
#include <hip/hip_runtime.h>
#include <hip/hip_bf16.h>

#define M_DIM 4096
#define N_DIM 8192
#define K_DIM 8192

using bf16x8 = __attribute__((ext_vector_type(8))) short;
using f32x4  = __attribute__((ext_vector_type(4))) float;

static __device__ __forceinline__ unsigned short f32_to_bf16_rne(float f) {
    unsigned u = __float_as_uint(f);
    unsigned rounding = 0x7FFFu + ((u >> 16) & 1u);
    u += rounding;
    return (unsigned short)(u >> 16);
}

// ---------------- zero W (f32) ----------------
__global__ void zero_kernel(float4* __restrict__ p, int n4) {
    int i = blockIdx.x * blockDim.x + threadIdx.x;
    int stride = gridDim.x * blockDim.x;
    float4 z = make_float4(0.f, 0.f, 0.f, 0.f);
    for (; i < n4; i += stride) p[i] = z;
}

// ---------------- scatter-add COO ----------------
__global__ void scatter_kernel(const float* __restrict__ vals,
                               const int* __restrict__ rows,
                               const int* __restrict__ cols,
                               float* __restrict__ W, int n) {
    int i = blockIdx.x * blockDim.x + threadIdx.x;
    if (i < n) {
        atomicAdd(&W[(size_t)rows[i] * K_DIM + cols[i]], vals[i]);
    }
}

// ---------------- f32 -> bf16 cast ----------------
__global__ void cvt_bf16_kernel(const float4* __restrict__ src,
                                ushort4* __restrict__ dst, int n4) {
    int i = blockIdx.x * blockDim.x + threadIdx.x;
    int stride = gridDim.x * blockDim.x;
    for (; i < n4; i += stride) {
        float4 v = src[i];
        ushort4 o;
        o.x = f32_to_bf16_rne(v.x);
        o.y = f32_to_bf16_rne(v.y);
        o.z = f32_to_bf16_rne(v.z);
        o.w = f32_to_bf16_rne(v.w);
        dst[i] = o;
    }
}

// ---------------- zero d_out fallback (ws too small diagnostic) ----------------
__global__ void zero_out_kernel(float* __restrict__ p, int n) {
    int i = blockIdx.x * blockDim.x + threadIdx.x;
    int stride = gridDim.x * blockDim.x;
    for (; i < n; i += stride) p[i] = 0.f;
}

// ---------------- bf16 NT GEMM, 256x256 8-phase (T2+T3+T4+T5) ----------------
// C[M][N] = A[M][K] * B[N][K]^T.  BM=BN=256, BK=64, 8 waves (2M x 4N),
// per-wave output 128x64 (acc[8][4] f32x4).  LDS 128 KiB:
// [db][op A/B][half 128rows][128][64] bf16, double-buffered.
// Per K-tile: 4 phases of {ds_read subtile | stage 1 half-tile | barrier |
// lgkmcnt(0) | setprio(1) 16 MFMA setprio(0) | barrier}; vmcnt(4) only at
// tile boundaries (counted, T4).  Staging schedule (liveness-verified):
//   p0: A half0 of t+1 (other dbuf; dead since t-1 end)
//   p1: A half1 of t+1
//   p2: B half0 of t+2 (current dbuf B region; dead after p0 - B is in regs)
//   p3: B half1 of t+2
// Boundary vmcnt(4) leaves exactly the B(t+2) pair in flight.
// LDS swizzle (T2, rule #21): slot (row,c) holds global k-chunk c^(row&7);
// staging pre-swizzles the global source, reads apply the same involution.
__global__ __launch_bounds__(512, 2) void gemm_bt(const ushort* __restrict__ A,
                                                  const ushort* __restrict__ B,
                                                  float* __restrict__ C) {
    constexpr int BM = 256, BN = 256, BK = 64;
    constexpr int NT = K_DIM / BK;     // 128 K-tiles
    __shared__ ushort lds[65536];      // 128 KiB

    const int nbn = N_DIM / BN;        // 32
    const int bm = blockIdx.x / nbn;
    const int bn = blockIdx.x % nbn;
    const int brow = bm * BM, bcol = bn * BN;

    const int t    = threadIdx.x;
    const int lane = t & 63;
    const int wid  = t >> 6;           // 0..7
    const int wm   = wid >> 2;         // 0..1 (M)
    const int wn   = wid & 3;          // 0..3 (N)
    const int lrow = lane & 15;
    const int ghi  = lane >> 4;        // 0..3

    // read-side swizzled k-chunk per lane (same for A and B; row&7 == lrow&7)
    const int c0 = (0 + ghi) ^ (lrow & 7);   // ksub 0
    const int c1 = (4 + ghi) ^ (lrow & 7);   // ksub 1

    f32x4  acc[8][4] = {};
    bf16x8 bfr[4][2];                  // B frags, live across one tile

    // stage one 128x64 half-tile: 512 thr x 2 x 16B. Linear LDS dest,
    // source k-chunk pre-swizzled: (fl&7) ^ ((fl>>3)&7).
    auto stage_half = [&](int db, int op, int half, int ktile) {
        const ushort* G = (op == 0) ? A : B;
        const int rbase = ((op == 0) ? brow : bcol) + half * 128;
        #pragma unroll
        for (int i = 0; i < 2; ++i) {
            int fl  = i * 512 + t;                 // 0..1023
            int row = fl >> 3;
            int cc  = (fl & 7) ^ (row & 7);
            const ushort* src = G + (size_t)(rbase + row) * K_DIM + ktile * BK + cc * 8;
            __builtin_amdgcn_global_load_lds(
                (const __attribute__((address_space(1))) void*)src,
                (__attribute__((address_space(3))) void*)
                    (&lds[db * 32768 + op * 16384 + half * 8192 + fl * 8]),
                16, 0, 0);
        }
    };

    auto tile_body = [&](int tt, int db, bool stgA, bool stgB, int vm) {
        const ushort* Ah = &lds[db * 32768 + wm * 8192];
        const ushort* Bh = &lds[db * 32768 + 16384 + (wn >> 1) * 8192 + (wn & 1) * 4096];
        const ushort* a0 = Ah + lrow * 64 + c0 * 8;
        const ushort* a1 = Ah + lrow * 64 + c1 * 8;
        const ushort* b0 = Bh + lrow * 64 + c0 * 8;
        const ushort* b1 = Bh + lrow * 64 + c1 * 8;
        #pragma unroll
        for (int q = 0; q < 4; ++q) {
            bf16x8 af[2][2];
            if (q == 0) {
                #pragma unroll
                for (int n = 0; n < 4; ++n) {
                    bfr[n][0] = *(const bf16x8*)(b0 + n * 1024);
                    bfr[n][1] = *(const bf16x8*)(b1 + n * 1024);
                }
            }
            #pragma unroll
            for (int j = 0; j < 2; ++j) {
                af[j][0] = *(const bf16x8*)(a0 + (2 * q + j) * 1024);
                af[j][1] = *(const bf16x8*)(a1 + (2 * q + j) * 1024);
            }
            if (q == 0 && stgA) stage_half(db ^ 1, 0, 0, tt + 1);
            if (q == 1 && stgA) stage_half(db ^ 1, 0, 1, tt + 1);
            if (q == 2 && stgB) stage_half(db,     1, 0, tt + 2);
            if (q == 3 && stgB) stage_half(db,     1, 1, tt + 2);
            __builtin_amdgcn_s_barrier();
            asm volatile("s_waitcnt lgkmcnt(0)" ::: "memory");
            __builtin_amdgcn_s_setprio(1);
            #pragma unroll
            for (int j = 0; j < 2; ++j)
                #pragma unroll
                for (int n = 0; n < 4; ++n) {
                    acc[2 * q + j][n] = __builtin_amdgcn_mfma_f32_16x16x32_bf16(
                        af[j][0], bfr[n][0], acc[2 * q + j][n], 0, 0, 0);
                    acc[2 * q + j][n] = __builtin_amdgcn_mfma_f32_16x16x32_bf16(
                        af[j][1], bfr[n][1], acc[2 * q + j][n], 0, 0, 0);
                }
            __builtin_amdgcn_s_setprio(0);
            if (q == 3) {
                if (vm == 4) asm volatile("s_waitcnt vmcnt(4)" ::: "memory");
                else         asm volatile("s_waitcnt vmcnt(0)" ::: "memory");
            }
            __builtin_amdgcn_s_barrier();
        }
    };

    // ---- prologue: tile 0 fully + B(1); drain to 4 (B(1) stays in flight) ----
    stage_half(0, 0, 0, 0);
    stage_half(0, 0, 1, 0);
    stage_half(0, 1, 0, 0);
    stage_half(0, 1, 1, 0);
    stage_half(1, 1, 0, 1);
    stage_half(1, 1, 1, 1);
    asm volatile("s_waitcnt vmcnt(4)" ::: "memory");
    __builtin_amdgcn_s_barrier();

    // ---- main loop: tiles 0..NT-3 with full staging, vmcnt(4) ----
    for (int tt = 0; tt < NT - 2; tt += 2) {
        tile_body(tt,     0, true, true, 4);
        tile_body(tt + 1, 1, true, true, 4);
    }
    // ---- peeled tail: t=NT-2 stages A(NT-1) only, then drain; t=NT-1 bare ----
    tile_body(NT - 2, 0, true,  false, 0);
    tile_body(NT - 1, 1, false, false, 0);

    // ---- epilogue: C/D layout col=lane&15, row=(lane>>4)*4+r ----
    const int crow0 = brow + wm * 128;
    const int ccol0 = bcol + wn * 64;
    #pragma unroll
    for (int m = 0; m < 8; ++m) {
        #pragma unroll
        for (int n = 0; n < 4; ++n) {
            int col   = ccol0 + n * 16 + lrow;
            int rbase = crow0 + m * 16 + (lane >> 4) * 4;
            #pragma unroll
            for (int r = 0; r < 4; ++r)
                C[(size_t)(rbase + r) * N_DIM + col] = acc[m][n][r];
        }
    }
}

extern "C" void kernel_launch(void* const* d_in, const int* in_sizes, int n_in,
                              void* d_out, int out_size, void* d_ws, size_t ws_size,
                              hipStream_t stream) {
    const float* x    = (const float*)d_in[0];
    const float* vals = (const float*)d_in[1];
    const int* rows   = (const int*)d_in[2];
    const int* cols   = (const int*)d_in[3];
    float* out        = (float*)d_out;
    const int n_items = in_sizes[1];

    const size_t W_F32_BYTES  = (size_t)N_DIM * K_DIM * 4;  // 256 MiB
    const size_t W_BF16_BYTES = (size_t)N_DIM * K_DIM * 2;  // 128 MiB
    const size_t X_BF16_BYTES = (size_t)M_DIM * K_DIM * 2;  //  64 MiB
    const size_t NEEDED = W_F32_BYTES + W_BF16_BYTES + X_BF16_BYTES;

    if (ws_size < NEEDED) {
        // Diagnostic fallback: clean absmax=126 failure signals ws too small.
        zero_out_kernel<<<2048, 256, 0, stream>>>(out, out_size);
        return;
    }

    char* ws = (char*)d_ws;
    float* Wf  = (float*)ws;
    ushort* Wb = (ushort*)(ws + W_F32_BYTES);
    ushort* Xb = (ushort*)(ws + W_F32_BYTES + W_BF16_BYTES);

    // 1) zero W (re-zeroed every call: deterministic under replay)
    zero_kernel<<<2048, 256, 0, stream>>>((float4*)Wf, (N_DIM * K_DIM) / 4);
    // 2) scatter-add nonzeros
    scatter_kernel<<<(n_items + 255) / 256, 256, 0, stream>>>(vals, rows, cols, Wf, n_items);
    // 3) cast W and x to bf16
    cvt_bf16_kernel<<<2048, 256, 0, stream>>>((const float4*)Wf, (ushort4*)Wb,
                                              (N_DIM * K_DIM) / 4);
    cvt_bf16_kernel<<<2048, 256, 0, stream>>>((const float4*)x, (ushort4*)Xb,
                                              (M_DIM * K_DIM) / 4);
    // 4) GEMM: out = Xb (M x K) * Wb (N x K)^T  -- 512 blocks of 512 threads
    gemm_bt<<<(M_DIM / 256) * (N_DIM / 256), 512, 0, stream>>>(Xb, Wb, out);
}